// Round 7
// baseline (600.436 us; speedup 1.0000x reference)
//
#include <hip/hip_runtime.h>
#include <stdint.h>

#define GAS __attribute__((address_space(1)))
#define LAS __attribute__((address_space(3)))

typedef __attribute__((ext_vector_type(8))) short short8;
typedef __attribute__((ext_vector_type(4))) float float4v;
typedef __attribute__((ext_vector_type(4))) unsigned int uint4v;

__device__ __forceinline__ unsigned short f2bf(float f) {
  union { float f; unsigned int u; } v; v.f = f;
  unsigned int r = v.u + 0x7fffu + ((v.u >> 16) & 1u);
  return (unsigned short)(r >> 16);
}

__device__ __forceinline__ void async_g2l16(const void* g, void* l) {
  __builtin_amdgcn_global_load_lds((const GAS unsigned int*)g,
                                   (LAS unsigned int*)l, 16, 0, 0);
}

__device__ __forceinline__ void vmem_drain() {
  asm volatile("s_waitcnt vmcnt(0)" ::: "memory");
}

// ---- Kernel A: normalize y -> bf16 fragment-major [t][og][cb][lane][8] ----
// For t=dy*16+dx: fragment (og,cb) is 1KB; lane = q*16 + (o&15), holds
// o = og*16+(o&15), c = cb*32 + q*8 + j  (exactly the 16x16x32 B-operand map).
__global__ void knorm_y(const float* __restrict__ y, unsigned short* __restrict__ y_t2) {
  int o = blockIdx.x;
  int tid = threadIdx.x;
  const float* yo = y + o * 16384;
  float s = 0.f;
  for (int idx = tid; idx < 16384; idx += 256) { float v = yo[idx]; s += v * v; }
  for (int off = 32; off; off >>= 1) s += __shfl_down(s, off, 64);
  __shared__ float red[4];
  if ((tid & 63) == 0) red[tid >> 6] = s;
  __syncthreads();
  float rn = 1.0f / sqrtf(red[0] + red[1] + red[2] + red[3]);
  int og = o >> 4, ol = o & 15;
  for (int idx = tid; idx < 16384; idx += 256) {
    int c = idx >> 8, dy = (idx >> 4) & 15, dx = idx & 15;
    int t = dy * 16 + dx;
    int cb = c >> 5, q = (c >> 3) & 3, j = c & 7;
    size_t dst = (size_t)t * 4096 + (size_t)(og * 2 + cb) * 512 + (q * 16 + ol) * 8 + j;
    y_t2[dst] = f2bf(yo[idx] * rn);
  }
}

// ------- Kernel B: x (NCHW f32) -> x_t bf16 [n][h][w][c] swizzled, + s -----
__global__ void ktrans_x(const float* __restrict__ x, unsigned short* __restrict__ x_t,
                         float* __restrict__ s) {
  int h = blockIdx.x, n = blockIdx.y;
  int tid = threadIdx.x;
  __shared__ __align__(16) unsigned short tb[8192];
  __shared__ float sb[256];
  const float* xb = x + ((size_t)n * 64) * 16384 + h * 128;
  int w = tid & 127, half = tid >> 7;
  float acc = 0.f;
#pragma unroll
  for (int cs = 0; cs < 4; ++cs) {
    short8 tmp;
#pragma unroll
    for (int j = 0; j < 8; ++j) {
      int c = half * 32 + cs * 8 + j;
      float v = xb[(size_t)c * 16384 + w];
      tmp[j] = (short)f2bf(v);
      acc += v * v;
    }
    int chunk = (half * 4 + cs) ^ (w & 7);
    *(short8*)(tb + w * 64 + chunk * 8) = tmp;
  }
  sb[tid] = acc;
  __syncthreads();
  uint4v* dst = (uint4v*)(x_t + ((size_t)(n * 128 + h)) * 8192);
  const uint4v* src = (const uint4v*)tb;
  for (int idx = tid; idx < 1024; idx += 256) dst[idx] = src[idx];
  if (tid < 128) s[((size_t)(n * 128 + h)) * 128 + tid] = sb[tid] + sb[tid + 128];
}

// ---------------- Kernel D: separable 16x16 box sum of s -> 1/sqrt --------
__global__ void knorm_x(const float* __restrict__ s, float* __restrict__ invn) {
  int i = blockIdx.x, n = blockIdx.y;
  int tid = threadIdx.x;  // 128
  __shared__ float colsum[128];
  const float* sp = s + ((size_t)(n * 128 + i)) * 128;
  float a = 0.f;
#pragma unroll
  for (int dy = 0; dy < 16; ++dy) a += sp[dy * 128 + tid];
  colsum[tid] = a;
  __syncthreads();
  if (tid < 113) {
    float acc = 0.f;
#pragma unroll
    for (int dx = 0; dx < 16; ++dx) acc += colsum[tid + dx];
    invn[((size_t)n * 113 + i) * 113 + tid] = 1.0f / sqrtf(acc);
  }
}

// ---------------- Kernel E: main implicit-GEMM conv -----------------------
// R6: A-LDS pipe is the top pipe (694K cyc/CU = 72% > MFMA 561K = 58%);
// MfmaUtil pinned ~60% through R4 (locality) and R5 (B depth/setprio) -> only
// LDS reads per MFMA can move it. New decomposition: block = n-PAIR x row i
// (M=256, grid 904 = 113 x 8 n-pairs). 4 waves of M64 x N64: each A row-panel
// read by exactly ONE wave (-50% LDS reads per output); B: 4 waves load the
// same fragments (L1-coalesced, per-row L2 traffic unchanged). Single-buffer
// A (2 rows x 16KB + 2KB overrun pad for the j+dx sliding window); per-dy
// barrier/stage/drain/barrier; stall hidden by 3 blocks/CU. Direct-store
// epilogue (R3-verified). XCD swizzle: npair = lin&7 -> each XCD owns one
// n-pair (x_t 2MB + y_t2 2MB = 4MB = one L2).
__launch_bounds__(256, 3)
__global__ void kconv(const unsigned short* __restrict__ x_t,
                      const unsigned short* __restrict__ y_t2,
                      const float* __restrict__ invn,
                      float* __restrict__ out) {
  int lin = blockIdx.y * 113 + blockIdx.x;
  int npair = lin & 7;        // consecutive lin round-robin XCDs -> npair==XCD
  int i = lin >> 3;           // 0..112
  int n0 = npair * 2;
  int tid = threadIdx.x;
  int lane = tid & 63, wave = tid >> 6;
  int lane15 = lane & 15, q = lane >> 4;
  int nn = wave >> 1;         // which image of the pair
  int jh = wave & 1;          // j half (0: 0-63, 1: 64-127)

  __shared__ __align__(16) char smem[34816];  // 2 x 16KB rows + 2KB overrun pad

  auto stageA2 = [&](int dy) {
#pragma unroll
    for (int r = 0; r < 2; ++r) {
      const char* src = (const char*)(x_t + ((size_t)((n0 + r) * 128 + i + dy)) * 8192);
#pragma unroll
      for (int it = 0; it < 4; ++it) {
        int chunk = it * 256 + wave * 64;  // wave-uniform LDS base
        async_g2l16(src + (chunk + lane) * 16, smem + r * 16384 + chunk * 16);
      }
    }
  };

  const short8* ybase = (const short8*)y_t2 + lane;
  auto loadB = [&](int t, short8 bf[4][2]) {
    const short8* p = ybase + (size_t)t * 512;  // 512 short8 = 4096 shorts per t
#pragma unroll
    for (int nt = 0; nt < 4; ++nt) {
      bf[nt][0] = p[nt * 128];
      bf[nt][1] = p[nt * 128 + 64];
    }
  };

  float4v acc[4][4];
#pragma unroll
  for (int mt = 0; mt < 4; ++mt)
#pragma unroll
    for (int nt = 0; nt < 4; ++nt) acc[mt][nt] = (float4v){0.f, 0.f, 0.f, 0.f};

  int abase[4];
#pragma unroll
  for (int mt = 0; mt < 4; ++mt)
    abase[mt] = nn * 16384 + (jh * 64 + mt * 16 + lane15) * 128;

  short8 b0[4][2], b1[4][2];
  stageA2(0);
  loadB(0, b0);
  vmem_drain();
  __syncthreads();

#pragma unroll 1
  for (int dy = 0; dy < 16; ++dy) {
#pragma unroll
    for (int dx = 0; dx < 16; ++dx) {
      int t = dy * 16 + dx;
      // compile-time ping-pong (16 even -> dx&1 == t&1, phase dy-invariant)
      short8(&bc)[4][2] = (dx & 1) ? b1 : b0;
      short8(&bn)[4][2] = (dx & 1) ? b0 : b1;
      if (t < 255) loadB(t + 1, bn);
      int xr = (lane15 + dx) & 7;
#pragma unroll
      for (int cb = 0; cb < 2; ++cb) {
        int aoff = dx * 128 + (((q + cb * 4) ^ xr) << 4);
#pragma unroll
        for (int mt = 0; mt < 4; ++mt) {
          short8 a = *(const short8*)(smem + abase[mt] + aoff);
#pragma unroll
          for (int nt = 0; nt < 4; ++nt)
            acc[mt][nt] = __builtin_amdgcn_mfma_f32_16x16x32_bf16(a, bc[nt][cb], acc[mt][nt], 0, 0, 0);
        }
      }
    }
    if (dy < 15) {
      __syncthreads();   // all waves done reading A rows of this dy
      stageA2(dy + 1);
      vmem_drain();      // stage landed (in-flight bn also drains; it is old)
      __syncthreads();
    }
  }

  // Epilogue: direct stores. C/D map (16x16x32): o = nt*16 + lane15,
  // j = jh*64 + mt*16 + q*4 + reg  -> regs 0..3 are contiguous j.
  int n = n0 + nn;
  const float* ivp = invn + ((size_t)n * 113 + i) * 113;
  float* op = out + (size_t)n * 64 * 12769 + (size_t)i * 113;
  int jbase = jh * 64 + q * 4;
#pragma unroll
  for (int mt = 0; mt < 4; ++mt) {
    int j0 = jbase + mt * 16;
    if (j0 <= 108) {
      float4v iv = *(const float4v*)(ivp + j0);
#pragma unroll
      for (int nt = 0; nt < 4; ++nt) {
        int o = nt * 16 + lane15;
        float4v v = acc[mt][nt];
        float4v r;
        r[0] = fmaxf(v[0] * iv[0], 0.f);
        r[1] = fmaxf(v[1] * iv[1], 0.f);
        r[2] = fmaxf(v[2] * iv[2], 0.f);
        r[3] = fmaxf(v[3] * iv[3], 0.f);
        *(float4v*)(op + (size_t)o * 12769 + j0) = r;
      }
    } else if (j0 == 112) {
      float ivs = ivp[112];
#pragma unroll
      for (int nt = 0; nt < 4; ++nt) {
        int o = nt * 16 + lane15;
        op[(size_t)o * 12769 + 112] = fmaxf(acc[mt][nt][0] * ivs, 0.f);
      }
    }
  }
}

extern "C" void kernel_launch(void* const* d_in, const int* in_sizes, int n_in,
                              void* d_out, int out_size, void* d_ws, size_t ws_size,
                              hipStream_t stream) {
  const float* x = (const float*)d_in[0];
  const float* y = (const float*)d_in[1];
  float* out = (float*)d_out;
  char* ws = (char*)d_ws;
  unsigned short* x_t = (unsigned short*)ws;                 // 33,554,432 B
  unsigned short* y_t2 = (unsigned short*)(ws + 33554432);   //  2,097,152 B
  float* s = (float*)(ws + 35651584);                        //  1,048,576 B
  float* invn = (float*)(ws + 36700160);                     //    817,216 B

  hipLaunchKernelGGL(knorm_y, dim3(64), dim3(256), 0, stream, y, y_t2);
  hipLaunchKernelGGL(ktrans_x, dim3(128, 16), dim3(256), 0, stream, x, x_t, s);
  hipLaunchKernelGGL(knorm_x, dim3(113, 16), dim3(128), 0, stream, s, invn);
  hipLaunchKernelGGL(kconv, dim3(113, 8), dim3(256), 0, stream, x_t, y_t2, invn, out);
}